// Round 10
// baseline (197.795 us; speedup 1.0000x reference)
//
#include <hip/hip_runtime.h>
#include <hip/hip_bf16.h>
#include <math.h>

// GNNAngle round 10: persistent mega-blocks. 256 blocks x 1024 threads (one
// per CU), all 3 weight layers staged ONCE per block into LDS (f16, [j][i],
// stride 132 -> conflict-light ds_read_b128), grid-stride over 64-node chunks.
// Kills: per-block weight re-fetch (600 MB -> 49 MB), prep kernel, 6250-block
// launch overhead. Phase A = R9 structure; next chunk's loads issue under
// phase B's barriers/MFMA.

#define NTHREADS 1024   // 16 waves
#define CHUNK    64     // nodes per chunk
#define ASTRIDE  136    // f16 act row stride
#define WSTRIDE  132    // f16 weight row stride (2*lr bank spread)
#define NBLOCKS  256

typedef _Float16 f16;
typedef f16  f16x8 __attribute__((ext_vector_type(8)));
typedef f16  f16x4 __attribute__((ext_vector_type(4)));
typedef float f32x4 __attribute__((ext_vector_type(4)));

__device__ __forceinline__ float fast_tanh(float x) {
    float e = __expf(2.0f * x);
    return 1.0f - 2.0f * __builtin_amdgcn_rcpf(e + 1.0f);
}

__device__ __forceinline__ float fast_acos(float x) {
    // Abramowitz-Stegun 4.4.45: max abs error 6.7e-5 rad, branchless
    float ax = fabsf(x);
    float p = fmaf(-0.0187293f, ax, 0.0742610f);
    p = fmaf(p, ax, -0.2121144f);
    p = fmaf(p, ax, 1.5707288f);
    float r = sqrtf(1.0f - ax) * p;
    return (x >= 0.0f) ? r : (3.14159265358979f - r);
}

// per-node Gram+acos: c0/c1 hold row lr, dims lg*8..+8; writes angles to actF row m
__device__ __forceinline__ void gram_acos_node(float4 c0, float4 c1, int m,
                                               int lr, int lg, f16* actF)
{
    float ss = c0.x*c0.x + c0.y*c0.y + c0.z*c0.z + c0.w*c0.w
             + c1.x*c1.x + c1.y*c1.y + c1.z*c1.z + c1.w*c1.w;
    ss += __shfl_xor(ss, 16);
    ss += __shfl_xor(ss, 32);
    const float sc = __builtin_amdgcn_rsqf(ss + 1e-24f);
    f16x8 frag;
    frag[0] = (f16)(c0.x * sc); frag[1] = (f16)(c0.y * sc);
    frag[2] = (f16)(c0.z * sc); frag[3] = (f16)(c0.w * sc);
    frag[4] = (f16)(c1.x * sc); frag[5] = (f16)(c1.y * sc);
    frag[6] = (f16)(c1.z * sc); frag[7] = (f16)(c1.w * sc);
    f32x4 acc = {0.f, 0.f, 0.f, 0.f};
    acc = __builtin_amdgcn_mfma_f32_16x16x32_f16(frag, frag, acc, 0, 0, 0);
    const int col = lr;
    #pragma unroll
    for (int r2 = 0; r2 < 4; ++r2) {
        const int row = lg * 4 + r2;
        float c = fminf(fmaxf(acc[r2], -1.0f + 1e-7f), 1.0f - 1e-7f);
        float ang = fast_acos(c);
        if (row < col) {
            const int p = 15 * row - ((row * (row - 1)) >> 1) + (col - row - 1);
            actF[m * ASTRIDE + p] = (f16)ang;
        }
    }
}

// one MLP layer, weights from LDS: dst[node][j] = tanh(sum_i src[i]*W[j][i]+b[j])
// wave: jt = w>>1 (j-tile 0..7), node-tiles ntb, ntb+1 (ntb = (w&1)*2)
__device__ __forceinline__ void mlp_layer_lds(const f16* __restrict__ wl,   // LDS [128][WSTRIDE]
                                              f32x4 bv,
                                              const f16* src, f16* dst,     // LDS, stride ASTRIDE
                                              int jt, int ntb, int lr, int lg)
{
    const f16* wr = wl + (jt * 16 + lr) * WSTRIDE + lg * 8;
    f16x8 a0 = *(const f16x8*)(wr);
    f16x8 a1 = *(const f16x8*)(wr + 32);
    f16x8 a2 = *(const f16x8*)(wr + 64);
    f16x8 a3 = *(const f16x8*)(wr + 96);
    #pragma unroll
    for (int k = 0; k < 2; ++k) {
        const int node = (ntb + k) * 16 + lr;
        const f16* sr = src + node * ASTRIDE + lg * 8;
        f16x8 bf0 = *(const f16x8*)(sr);
        f16x8 bf1 = *(const f16x8*)(sr + 32);
        f16x8 bf2 = *(const f16x8*)(sr + 64);
        f16x8 bf3 = *(const f16x8*)(sr + 96);
        f32x4 acc = {0.f, 0.f, 0.f, 0.f};
        acc = __builtin_amdgcn_mfma_f32_16x16x32_f16(a0, bf0, acc, 0, 0, 0);
        acc = __builtin_amdgcn_mfma_f32_16x16x32_f16(a1, bf1, acc, 0, 0, 0);
        acc = __builtin_amdgcn_mfma_f32_16x16x32_f16(a2, bf2, acc, 0, 0, 0);
        acc = __builtin_amdgcn_mfma_f32_16x16x32_f16(a3, bf3, acc, 0, 0, 0);
        f16x4 o;
        #pragma unroll
        for (int r = 0; r < 4; ++r)
            o[r] = (f16)fast_tanh(acc[r] + bv[r]);
        *(f16x4*)(dst + node * ASTRIDE + jt * 16 + lg * 4) = o;
    }
}

__global__ __launch_bounds__(NTHREADS, 4)
void gnn_persist(const float* __restrict__ edge_attr,
                 const float* __restrict__ W1, const float* __restrict__ b1,
                 const float* __restrict__ W2, const float* __restrict__ b2,
                 const float* __restrict__ W3, const float* __restrict__ b3,
                 const float* __restrict__ W4, const float* __restrict__ b4,
                 float* __restrict__ out, int n_nodes, int nchunks)
{
    __shared__ __attribute__((aligned(16))) f16 wlds[3 * 128 * WSTRIDE];  // 101.4 KB
    __shared__ __attribute__((aligned(16))) f16 acts0[CHUNK * ASTRIDE];   // 17.4 KB
    __shared__ __attribute__((aligned(16))) f16 acts1[CHUNK * ASTRIDE];   // 17.4 KB

    const int t  = threadIdx.x;
    const int w  = t >> 6;     // wave 0..15
    const int l  = t & 63;
    const int lr = l & 15;
    const int lg = l >> 4;

    // ---- stage all weights once: W[i][j] f32 -> wlds[layer][j][i] f16 ----
    #pragma unroll 4
    for (int k = 0; k < 48; ++k) {
        const int idx   = t + k * 1024;
        const int layer = idx >> 14;
        const int rem   = idx & 16383;
        const int i     = rem >> 7;
        const int j     = rem & 127;        // consecutive t -> consecutive j (coalesced)
        const float* W  = (layer == 0) ? W1 : ((layer == 1) ? W2 : W3);
        const int in_l  = (layer == 0) ? 120 : 128;
        const float v   = (i < in_l) ? W[i * 128 + j] : 0.0f;
        wlds[layer * (128 * WSTRIDE) + j * WSTRIDE + i] = (f16)v;
    }

    // ---- hoisted per-thread constants ----
    const int jt  = w >> 1;          // j-tile 0..7
    const int ntb = (w & 1) * 2;     // node-tile base 0 or 2
    const f32x4 bv1 = *(const f32x4*)(b1 + jt * 16 + lg * 4);
    const f32x4 bv2 = *(const f32x4*)(b2 + jt * 16 + lg * 4);
    const f32x4 bv3 = *(const f32x4*)(b3 + jt * 16 + lg * 4);
    const int fpart = t & 15;        // final layer: 16 threads/node
    const f32x4 w4a = *(const f32x4*)(W4 + fpart * 8);
    const f32x4 w4b = *(const f32x4*)(W4 + fpart * 8 + 4);
    const float bb4 = b4[0];

    // ---- preload first chunk: wave w owns nodes c*16+w, c=0..3 ----
    long chunk = blockIdx.x;
    float4 d0a, d0b, d1a, d1b, d2a, d2b, d3a, d3b;
    #define LOADC(da, db, c, ch)                                                \
        {                                                                       \
            const long gn = (ch) * CHUNK + (c) * 16 + w;                        \
            da = make_float4(0.f,0.f,0.f,0.f); db = da;                         \
            if (gn < n_nodes) {                                                 \
                const float* s = edge_attr + gn * 512 + lr * 32 + lg * 8;       \
                da = *(const float4*)(s);                                       \
                db = *(const float4*)(s + 4);                                   \
            }                                                                   \
        }
    if (chunk < nchunks) {
        LOADC(d0a, d0b, 0, chunk) LOADC(d1a, d1b, 1, chunk)
        LOADC(d2a, d2b, 2, chunk) LOADC(d3a, d3b, 3, chunk)
    }
    __syncthreads();   // weights staged

    for (; chunk < nchunks; chunk += NBLOCKS) {
        // ---- phase A: Gram + acos from held regs -> acts0 ----
        if (t < 512)   // re-zero K-pad cols 120..127 (L2 clobbers them each chunk)
            acts0[(t >> 3) * ASTRIDE + 120 + (t & 7)] = (f16)0.f;
        gram_acos_node(d0a, d0b,      w, lr, lg, acts0);
        gram_acos_node(d1a, d1b, 16 + w, lr, lg, acts0);
        gram_acos_node(d2a, d2b, 32 + w, lr, lg, acts0);
        gram_acos_node(d3a, d3b, 48 + w, lr, lg, acts0);

        // ---- issue next chunk's loads (hide under phase B) ----
        const long nxt = chunk + NBLOCKS;
        float4 e0a, e0b, e1a, e1b, e2a, e2b, e3a, e3b;
        e0a=e0b=e1a=e1b=e2a=e2b=e3a=e3b=make_float4(0.f,0.f,0.f,0.f);
        if (nxt < nchunks) {
            LOADC(e0a, e0b, 0, nxt) LOADC(e1a, e1b, 1, nxt)
            LOADC(e2a, e2b, 2, nxt) LOADC(e3a, e3b, 3, nxt)
        }
        __syncthreads();

        // ---- phase B: 3 MFMA layers, weights from LDS ----
        mlp_layer_lds(wlds,                     bv1, acts0, acts1, jt, ntb, lr, lg);
        __syncthreads();
        mlp_layer_lds(wlds + 128 * WSTRIDE,     bv2, acts1, acts0, jt, ntb, lr, lg);
        __syncthreads();
        mlp_layer_lds(wlds + 2 * 128 * WSTRIDE, bv3, acts0, acts1, jt, ntb, lr, lg);
        __syncthreads();

        // ---- final 128->1 + sigmoid: 16 threads per node ----
        {
            const int node = t >> 4;     // 0..63
            const int i0   = fpart * 8;
            const f16* sr = acts1 + node * ASTRIDE + i0;
            f16x8 h = *(const f16x8*)(sr);
            float s = 0.f;
            s = fmaf((float)h[0], w4a[0], s); s = fmaf((float)h[1], w4a[1], s);
            s = fmaf((float)h[2], w4a[2], s); s = fmaf((float)h[3], w4a[3], s);
            s = fmaf((float)h[4], w4b[0], s); s = fmaf((float)h[5], w4b[1], s);
            s = fmaf((float)h[6], w4b[2], s); s = fmaf((float)h[7], w4b[3], s);
            s += __shfl_xor(s, 1);
            s += __shfl_xor(s, 2);
            s += __shfl_xor(s, 4);
            s += __shfl_xor(s, 8);
            if (fpart == 0) {
                const long g = chunk * CHUNK + node;
                if (g < n_nodes)
                    out[g] = __builtin_amdgcn_rcpf(1.0f + __expf(-(s + bb4)));
            }
        }
        __syncthreads();   // acts1 consumed before next chunk's L1 overwrites

        d0a=e0a; d0b=e0b; d1a=e1a; d1b=e1b;
        d2a=e2a; d2b=e2b; d3a=e3a; d3b=e3b;
    }
    #undef LOADC
}

extern "C" void kernel_launch(void* const* d_in, const int* in_sizes, int n_in,
                              void* d_out, int out_size, void* d_ws, size_t ws_size,
                              hipStream_t stream) {
    // inputs: 0:x 1:edge_index 2:edge_attr 3:k 4:W1 5:b1 6:W2 7:b2 8:W3 9:b3 10:W4 11:b4
    const float* edge_attr = (const float*)d_in[2];
    const float* W1 = (const float*)d_in[4];
    const float* b1 = (const float*)d_in[5];
    const float* W2 = (const float*)d_in[6];
    const float* b2 = (const float*)d_in[7];
    const float* W3 = (const float*)d_in[8];
    const float* b3 = (const float*)d_in[9];
    const float* W4 = (const float*)d_in[10];
    const float* b4 = (const float*)d_in[11];
    float* out = (float*)d_out;

    const int n_nodes = in_sizes[2] / 512;            // E*D / (16*32)
    const int nchunks = (n_nodes + CHUNK - 1) / CHUNK;
    const int blocks  = NBLOCKS < nchunks ? NBLOCKS : nchunks;

    gnn_persist<<<blocks, NTHREADS, 0, stream>>>(
        edge_attr, W1, b1, W2, b2, W3, b3, W4, b4, out, n_nodes, nchunks);
}